// Round 1
// baseline (51.050 us; speedup 1.0000x reference)
//
#include <hip/hip_runtime.h>

#define NUM_CLASSES 100
#define QUEUE_SIZE  256
#define FEATURE_DIM 1024
#define BATCH       4096
#define EPS         1e-12f

// ---------------------------------------------------------------------------
// Kernel 1: compute target row index for each batch element.
// rank[b] = #{ b' < b : labels[b'] == labels[b] }  (serial FIFO semantics)
// rowidx[b] = labels[b]*QUEUE_SIZE + (queue_ptr[labels[b]] + rank[b]) % QUEUE_SIZE
// One block of 256 threads handles 256 consecutive batch elements:
//   - LDS histogram of all labels BEFORE this chunk (global scan, strided)
//   - intra-chunk scan over <=255 LDS entries for the local rank
// ---------------------------------------------------------------------------
__global__ __launch_bounds__(256) void compute_slots_kernel(
    const int* __restrict__ labels,
    const int* __restrict__ queue_ptr,
    int* __restrict__ rowidx)
{
    __shared__ int hist[NUM_CLASSES];
    __shared__ int s_lab[256];

    const int tid = threadIdx.x;
    const int chunk_start = blockIdx.x * 256;

    for (int i = tid; i < NUM_CLASSES; i += 256) hist[i] = 0;
    __syncthreads();

    // histogram of labels[0 .. chunk_start)
    for (int j = tid; j < chunk_start; j += 256) {
        atomicAdd(&hist[labels[j]], 1);
    }
    s_lab[tid] = labels[chunk_start + tid];
    __syncthreads();

    const int lab = s_lab[tid];
    int rank = hist[lab];
    for (int j = 0; j < tid; ++j) {
        rank += (s_lab[j] == lab) ? 1 : 0;
    }
    const int slot = (queue_ptr[lab] + rank) & (QUEUE_SIZE - 1);
    rowidx[chunk_start + tid] = lab * QUEUE_SIZE + slot;
}

// ---------------------------------------------------------------------------
// Kernel 2: bulk copy queue -> out (float4 grid-stride)
// ---------------------------------------------------------------------------
__global__ __launch_bounds__(256) void copy_queue_kernel(
    const float4* __restrict__ src,
    float4* __restrict__ dst,
    int n4)
{
    int i = blockIdx.x * blockDim.x + threadIdx.x;
    const int stride = gridDim.x * blockDim.x;
    for (; i < n4; i += stride) {
        dst[i] = src[i];
    }
}

// ---------------------------------------------------------------------------
// Kernel 3: normalize each embedding row and scatter into out.
// One 256-thread block per batch row; each thread owns one float4 (1024 f32).
// ---------------------------------------------------------------------------
__global__ __launch_bounds__(256) void scatter_normalize_kernel(
    const float* __restrict__ emb,
    const int* __restrict__ rowidx,
    float* __restrict__ out)
{
    const int b   = blockIdx.x;
    const int tid = threadIdx.x;

    const float4* src = reinterpret_cast<const float4*>(emb + (long)b * FEATURE_DIM);
    float4 v = src[tid];

    float ss = v.x * v.x + v.y * v.y + v.z * v.z + v.w * v.w;
    // wave64 reduction
    #pragma unroll
    for (int off = 32; off > 0; off >>= 1) {
        ss += __shfl_down(ss, off, 64);
    }

    __shared__ float s_part[4];
    const int lane = tid & 63;
    const int wave = tid >> 6;
    if (lane == 0) s_part[wave] = ss;
    __syncthreads();

    const float total = s_part[0] + s_part[1] + s_part[2] + s_part[3];
    const float inv = 1.0f / fmaxf(sqrtf(total), EPS);

    float4 o;
    o.x = v.x * inv; o.y = v.y * inv; o.z = v.z * inv; o.w = v.w * inv;

    float4* dst = reinterpret_cast<float4*>(out + (long)rowidx[b] * FEATURE_DIM);
    dst[tid] = o;
}

// ---------------------------------------------------------------------------
extern "C" void kernel_launch(void* const* d_in, const int* in_sizes, int n_in,
                              void* d_out, int out_size, void* d_ws, size_t ws_size,
                              hipStream_t stream)
{
    const float* embeddings = (const float*)d_in[0];   // (4096, 1024) f32
    const int*   labels     = (const int*)d_in[1];     // (4096,) int
    const float* queue      = (const float*)d_in[2];   // (100, 256, 1024) f32
    const int*   queue_ptr  = (const int*)d_in[3];     // (100,) int

    float* out    = (float*)d_out;                     // (100, 256, 1024) f32
    int*   rowidx = (int*)d_ws;                        // 4096 ints scratch

    // 1) FIFO slot computation (16 blocks x 256 threads)
    compute_slots_kernel<<<BATCH / 256, 256, 0, stream>>>(labels, queue_ptr, rowidx);

    // 2) bulk copy queue -> out
    const int n4 = (NUM_CLASSES * QUEUE_SIZE * FEATURE_DIM) / 4;  // 6,553,600
    copy_queue_kernel<<<2048, 256, 0, stream>>>(
        (const float4*)queue, (float4*)d_out, n4);

    // 3) normalize + scatter (stream order guarantees it lands after the copy)
    scatter_normalize_kernel<<<BATCH, 256, 0, stream>>>(embeddings, rowidx, out);
}

// Round 3
// 47.727 us; speedup vs baseline: 1.0696x; 1.0696x over previous
//
#include <hip/hip_runtime.h>

#define NUM_CLASSES 100
#define QUEUE_SIZE  256
#define FEATURE_DIM 1024
#define BATCH       4096
#define TOTAL_ROWS  (NUM_CLASSES * QUEUE_SIZE)   // 25600
#define EPS         1e-12f

typedef float f32x4 __attribute__((ext_vector_type(4)));

// ---------------------------------------------------------------------------
// Kernel 1: compute FIFO target row per batch element and build inverse map.
// rank[b] = #{ b' < b : labels[b'] == labels[b] }  (serial FIFO semantics)
// row[b]  = labels[b]*QUEUE_SIZE + (queue_ptr[labels[b]] + rank[b]) % QUEUE_SIZE
// inv[row] = max over b mapping to row  (atomicMax == serial last-write-wins)
// inv must be pre-initialized to -1 (memsetAsync 0xFF on the stream).
// ---------------------------------------------------------------------------
__global__ __launch_bounds__(256) void compute_slots_kernel(
    const int* __restrict__ labels,
    const int* __restrict__ queue_ptr,
    int* __restrict__ inv)
{
    __shared__ int hist[NUM_CLASSES];
    __shared__ int s_lab[256];

    const int tid = threadIdx.x;
    const int chunk_start = blockIdx.x * 256;

    for (int i = tid; i < NUM_CLASSES; i += 256) hist[i] = 0;
    __syncthreads();

    // histogram of labels[0 .. chunk_start)
    for (int j = tid; j < chunk_start; j += 256) {
        atomicAdd(&hist[labels[j]], 1);
    }
    s_lab[tid] = labels[chunk_start + tid];
    __syncthreads();

    const int lab = s_lab[tid];
    int rank = hist[lab];
    for (int j = 0; j < tid; ++j) {
        rank += (s_lab[j] == lab) ? 1 : 0;
    }
    const int slot = (queue_ptr[lab] + rank) & (QUEUE_SIZE - 1);
    const int row  = lab * QUEUE_SIZE + slot;
    const int b    = chunk_start + tid;
    atomicMax(&inv[row], b);
}

// ---------------------------------------------------------------------------
// Kernel 2: fused per-row writer. One 256-thread block per queue row.
//   inv[row] >= 0  -> normalize embedding row inv[row], write it
//   inv[row] <  0  -> stream-copy queue row (nontemporal: no reuse)
// Each output row is written exactly once.
// ---------------------------------------------------------------------------
__global__ __launch_bounds__(256) void fused_write_kernel(
    const float* __restrict__ queue,
    const float* __restrict__ emb,
    const int* __restrict__ inv,
    float* __restrict__ out)
{
    const int row = blockIdx.x;
    const int tid = threadIdx.x;
    const long base = (long)row * FEATURE_DIM;

    const int b = inv[row];

    if (b < 0) {
        // plain copy path — nontemporal (no reuse)
        const f32x4* src = reinterpret_cast<const f32x4*>(queue + base);
        f32x4*       dst = reinterpret_cast<f32x4*>(out + base);
        f32x4 v = __builtin_nontemporal_load(&src[tid]);
        __builtin_nontemporal_store(v, &dst[tid]);
        return;
    }

    // normalize-and-scatter path
    const f32x4* src = reinterpret_cast<const f32x4*>(emb + (long)b * FEATURE_DIM);
    f32x4 v = src[tid];

    float ss = v.x * v.x + v.y * v.y + v.z * v.z + v.w * v.w;
    #pragma unroll
    for (int off = 32; off > 0; off >>= 1) {
        ss += __shfl_down(ss, off, 64);
    }

    __shared__ float s_part[4];
    const int lane = tid & 63;
    const int wave = tid >> 6;
    if (lane == 0) s_part[wave] = ss;
    __syncthreads();

    const float total = s_part[0] + s_part[1] + s_part[2] + s_part[3];
    const float inv_n = 1.0f / fmaxf(sqrtf(total), EPS);

    f32x4 o = v * inv_n;

    f32x4* dst = reinterpret_cast<f32x4*>(out + base);
    __builtin_nontemporal_store(o, &dst[tid]);
}

// ---------------------------------------------------------------------------
extern "C" void kernel_launch(void* const* d_in, const int* in_sizes, int n_in,
                              void* d_out, int out_size, void* d_ws, size_t ws_size,
                              hipStream_t stream)
{
    const float* embeddings = (const float*)d_in[0];   // (4096, 1024) f32
    const int*   labels     = (const int*)d_in[1];     // (4096,) int32
    const float* queue      = (const float*)d_in[2];   // (100, 256, 1024) f32
    const int*   queue_ptr  = (const int*)d_in[3];     // (100,) int32

    float* out = (float*)d_out;                        // (100, 256, 1024) f32
    int*   inv = (int*)d_ws;                           // 25600 ints scratch

    // 0) inv = -1  (hipMemsetAsync is graph-capture safe)
    (void)hipMemsetAsync(inv, 0xFF, TOTAL_ROWS * sizeof(int), stream);

    // 1) FIFO slot computation + inverse map (16 blocks x 256 threads)
    compute_slots_kernel<<<BATCH / 256, 256, 0, stream>>>(labels, queue_ptr, inv);

    // 2) fused copy/normalize-scatter: one block per queue row
    fused_write_kernel<<<TOTAL_ROWS, 256, 0, stream>>>(queue, embeddings, inv, out);
}